// Round 13
// baseline (320.763 us; speedup 1.0000x reference)
//
#include <hip/hip_runtime.h>

typedef __attribute__((ext_vector_type(8))) short bf16x8;
typedef __attribute__((ext_vector_type(4))) float f32x4;

#define NH 32
#define NKV 8
#define DH 128
#define HID 4096
#define SEQ 2048
#define MAXB 4
#define MAXS 2048

__device__ __forceinline__ unsigned short f2bf(float f) {
  unsigned int u = __builtin_bit_cast(unsigned int, f);
  u += 0x7fffu + ((u >> 16) & 1u);
  return (unsigned short)(u >> 16);
}

// ---------------- elementwise fp32 -> bf16 ----------------
__global__ void k_cvt_bf16(const float4* __restrict__ in, ushort4* __restrict__ out, int n4) {
  int i = blockIdx.x * 256 + threadIdx.x;
  if (i >= n4) return;
  float4 v = in[i];
  ushort4 o;
  o.x = f2bf(v.x); o.y = f2bf(v.y); o.z = f2bf(v.z); o.w = f2bf(v.w);
  out[i] = o;
}

// ------------- transpose + convert: w (K x N f32) -> wt (N x K bf16), 64x64 tiles -------------
__global__ void k_transpose_cvt(const float* __restrict__ w, unsigned short* __restrict__ wt,
                                int K, int N) {
  __shared__ float T[64][65];
  const int n0 = blockIdx.x * 64, k0 = blockIdx.y * 64;
  const int t = threadIdx.x;
  const int lr = t >> 4, lc = (t & 15) * 4;
#pragma unroll
  for (int i = 0; i < 4; ++i) {
    float4 v = *(const float4*)&w[(size_t)(k0 + lr + i * 16) * N + n0 + lc];
    T[lc + 0][lr + i * 16] = v.x;
    T[lc + 1][lr + i * 16] = v.y;
    T[lc + 2][lr + i * 16] = v.z;
    T[lc + 3][lr + i * 16] = v.w;
  }
  __syncthreads();
  const int wr = t >> 3, wcol = (t & 7) * 8;
#pragma unroll
  for (int i = 0; i < 2; ++i) {
    int r = wr + i * 32;
    uint4 u;
    u.x = f2bf(T[r][wcol + 0]) | ((unsigned)f2bf(T[r][wcol + 1]) << 16);
    u.y = f2bf(T[r][wcol + 2]) | ((unsigned)f2bf(T[r][wcol + 3]) << 16);
    u.z = f2bf(T[r][wcol + 4]) | ((unsigned)f2bf(T[r][wcol + 5]) << 16);
    u.w = f2bf(T[r][wcol + 6]) | ((unsigned)f2bf(T[r][wcol + 7]) << 16);
    *(uint4*)&wt[(size_t)(n0 + r) * K + k0 + wcol] = u;
  }
}

// ============ (128*AI)x(128*BI) 2-phase-per-K-tile GEMM (T2+T3+T4+T5) ============
// Stage ledger (2 merged phases/tile, re-derived):
//   phase A: reads Ah0,Bh0,Bh1 frags | stages (t+1).Ah1 + (t+1).Bh0
//   phase B: reads Ah1 frags        | stages (t+2).Ah0 + (t+2).Bh1
// Race discipline: lgkmcnt(0) BEFORE each barrier -> every wave's LDS reads are
// complete before any wave can cross the barrier and stage into that region.
// Boundary wait once per tile (end of phase B): vmcnt(AI+BI) -> all t+1 halves
// confirmed; phase-B stages (t+2) stay in flight. Never vmcnt(0) mid-loop.
// LDS rows 64 cols (128B) as 8x16B chunks, read-swizzle chunk ^= row&7, staged
// via pre-swizzled GLOBAL source (linear LDS dest) -> 0 bank conflicts.
// FUSE variant (QKV): no C write; epilogue stages fp32 acc in LDS (2x 64-row
// passes) and emits RoPE'd Q/K (bf16), fp32 K/V caches, and compact V bf16.

#define ASHP(b, h) ((unsigned short*)smem + ((b)*2 + (h)) * (4096 * AI))
#define BSHP(b, h) ((unsigned short*)(smem + 32768 * AI) + ((b)*2 + (h)) * (4096 * BI))

#define STAGE_T(dst, srcB, rowoff, t, NI)                                                  \
  {                                                                                        \
    const unsigned short* _s = (srcB) + (size_t)(rowoff)*K + (size_t)(t) * 64;             \
    _Pragma("unroll") for (int _i = 0; _i < (NI); ++_i)                                    \
        __builtin_amdgcn_global_load_lds(                                                  \
            (const __attribute__((address_space(1))) void*)(_s + (size_t)_i * 64 * K),     \
            (__attribute__((address_space(3))) void*)((char*)(dst) + _i * 8192 + ldsW),    \
            16, 0, 0);                                                                     \
  }

#define RD_A2(bufi, h)                                                                     \
  _Pragma("unroll") for (int mf = 0; mf < MFH; ++mf) {                                     \
    af[mf][0] = *(const bf16x8*)&ASHP(bufi, h)[aRow + mf * 1024 + cOff0];                  \
    af[mf][1] = *(const bf16x8*)&ASHP(bufi, h)[aRow + mf * 1024 + cOff1];                  \
  }

#define RD_B2(bufi, h, BQ)                                                                 \
  _Pragma("unroll") for (int nf = 0; nf < NFB; ++nf) {                                     \
    BQ[nf][0] = *(const bf16x8*)&BSHP(bufi, h)[bRow + nf * 1024 + cOff0];                  \
    BQ[nf][1] = *(const bf16x8*)&BSHP(bufi, h)[bRow + nf * 1024 + cOff1];                  \
  }

#define MF_Q2(qa, qb2, BQ)                                                                 \
  _Pragma("unroll") for (int ks = 0; ks < 2; ++ks)                                         \
  _Pragma("unroll") for (int mf = 0; mf < MFH; ++mf)                                       \
  _Pragma("unroll") for (int nf = 0; nf < NFB; ++nf)                                       \
      acc[(qa)*MFH + mf][(qb2)*NFB + nf] = __builtin_amdgcn_mfma_f32_16x16x32_bf16(        \
          af[mf][ks], BQ[nf][ks], acc[(qa)*MFH + mf][(qb2)*NFB + nf], 0, 0, 0);

template <int AI, int BI, bool FUSE>
__global__ __launch_bounds__(512, 2) void k_gemm(
    const unsigned short* __restrict__ A, const unsigned short* __restrict__ BT,
    float* __restrict__ C, int M, int N, int K, const float* __restrict__ cosP,
    const float* __restrict__ sinP, unsigned short* __restrict__ qb,
    unsigned short* __restrict__ kb, float* __restrict__ cko, float* __restrict__ cvo,
    unsigned short* __restrict__ vbf) {
  constexpr int MFH = 2 * AI;  // A fragments per half per wave
  constexpr int NFB = BI;      // B fragments per half per wave
  constexpr int BM = 128 * AI, BN = 128 * BI;
  __shared__ char smem[32768 * (AI + BI)];
  const int tid = threadIdx.x;
  const int wave = tid >> 6, lane = tid & 63, lhi = lane >> 4, llo = lane & 15;
  const int wr = wave >> 2, wc = wave & 3;
  const int m0 = blockIdx.y * BM, n0 = blockIdx.x * BN;

  const int grow = tid >> 3;
  const int gc = (tid & 7) ^ (grow & 7);
  const unsigned short* Ab = A + (size_t)(m0 + grow) * K + gc * 8;
  const unsigned short* Bb = BT + (size_t)(n0 + grow) * K + gc * 8;
  const int ldsW = (tid & 448) * 16;  // wave-uniform byte base; HW adds lane*16

  const int xorc = llo & 7;
  const int cOff0 = (lhi ^ xorc) * 8;
  const int cOff1 = ((4 + lhi) ^ xorc) * 8;
  const int aRow = (wr * 32 * AI + llo) * 64;
  const int bRow = (wc * 16 * BI + llo) * 64;

  f32x4 acc[2 * MFH][2 * NFB] = {};
  bf16x8 af[MFH][2], bq0[NFB][2], bq1[NFB][2];
  const int NT = K >> 6;

  // ---- prologue: tile0 fully + tile1 {Ah0, Bh1} (the phase-B(t-1) slots) ----
  STAGE_T(ASHP(0, 0), Ab, 0, 0, AI);
  STAGE_T(BSHP(0, 0), Bb, 0, 0, BI);
  STAGE_T(BSHP(0, 1), Bb, 64 * BI, 0, BI);
  STAGE_T(ASHP(0, 1), Ab, 64 * AI, 0, AI);
  STAGE_T(ASHP(1, 0), Ab, 0, 1, AI);
  STAGE_T(BSHP(1, 1), Bb, 64 * BI, 1, BI);
  asm volatile("" ::: "memory");
  asm volatile("s_waitcnt vmcnt(%0)" ::"i"(AI + BI) : "memory");  // tile0 confirmed
  __builtin_amdgcn_s_barrier();
  asm volatile("" ::: "memory");

  for (int t = 0; t < NT; ++t) {
    const int buf = t & 1, nbuf = buf ^ 1;
    // ---- phase A: quadrants (0,0) + (0,1) ----
    RD_A2(buf, 0);
    RD_B2(buf, 0, bq0);
    RD_B2(buf, 1, bq1);
    if (t + 1 < NT) {
      STAGE_T(ASHP(nbuf, 1), Ab, 64 * AI, t + 1, AI);
      STAGE_T(BSHP(nbuf, 0), Bb, 0, t + 1, BI);
    }
    asm volatile("" ::: "memory");
    asm volatile("s_waitcnt lgkmcnt(0)" ::: "memory");  // reads done BEFORE barrier
    __builtin_amdgcn_s_barrier();
    asm volatile("" ::: "memory");
    __builtin_amdgcn_s_setprio(1);
    MF_Q2(0, 0, bq0);
    MF_Q2(0, 1, bq1);
    __builtin_amdgcn_s_setprio(0);
    // ---- phase B: quadrants (1,1) + (1,0) ----
    RD_A2(buf, 1);
    if (t + 2 < NT) {
      STAGE_T(ASHP(buf, 0), Ab, 0, t + 2, AI);
      STAGE_T(BSHP(buf, 1), Bb, 64 * BI, t + 2, BI);
    }
    asm volatile("" ::: "memory");
    if (t < NT - 2) {
      asm volatile("s_waitcnt vmcnt(%0) lgkmcnt(0)" ::"i"(AI + BI) : "memory");
    } else {
      asm volatile("s_waitcnt vmcnt(0) lgkmcnt(0)" ::: "memory");  // drain for the tail
    }
    __builtin_amdgcn_s_barrier();
    asm volatile("" ::: "memory");
    __builtin_amdgcn_s_setprio(1);
    MF_Q2(1, 1, bq1);
    MF_Q2(1, 0, bq0);
    __builtin_amdgcn_s_setprio(0);
  }

  if constexpr (!FUSE) {
    // ---- plain epilogue: C write ----
#pragma unroll
    for (int mb = 0; mb < 2; ++mb)
#pragma unroll
      for (int mf = 0; mf < MFH; ++mf)
#pragma unroll
        for (int nb = 0; nb < 2; ++nb)
#pragma unroll
          for (int nf = 0; nf < NFB; ++nf)
#pragma unroll
            for (int r = 0; r < 4; ++r)
              C[(size_t)(m0 + mb * 64 * AI + wr * 32 * AI + mf * 16 + lhi * 4 + r) * N + n0 +
                nb * 64 * BI + wc * 16 * BI + nf * 16 + llo] =
                  acc[mb * MFH + mf][nb * NFB + nf][r];
  } else {
    // ---- fused epilogue (AI=1, BN=384): RoPE + cache/operand writes ----
    // Tf: 64 x 388 fp32 tile in LDS (row stride 1552 B, 16B-aligned).
    float* Tf = (float*)smem;
#pragma unroll
    for (int p2 = 0; p2 < 2; ++p2) {
      __builtin_amdgcn_s_barrier();  // prior pass reads / K-loop reads complete
#pragma unroll
      for (int mf = 0; mf < MFH; ++mf)
#pragma unroll
        for (int nb = 0; nb < 2; ++nb)
#pragma unroll
          for (int nf = 0; nf < NFB; ++nf)
#pragma unroll
            for (int r = 0; r < 4; ++r)
              Tf[(wr * 32 + mf * 16 + lhi * 4 + r) * 388 + nb * 64 * BI + wc * 16 * BI +
                 nf * 16 + llo] = acc[p2 * MFH + mf][nb * NFB + nf][r];
      __builtin_amdgcn_s_barrier();
#pragma unroll
      for (int it = 0; it < 6; ++it) {
        int tsk = it * 512 + tid;  // 64 rows x 48 8-col chunks
        int row = tsk / 48, ch8 = (tsk % 48) * 8;
        int s = m0 + p2 * 64 + row;
        int c = n0 + ch8;
        const float* Trow = &Tf[row * 388];
        if (c < 4096 || (c >= 4096 && c < 5120)) {
          // Q or K region: RoPE
          const bool isQ = (c < 4096);
          int d = c & 127;
          const bool hi = d >= 64;
          int dd = d & 63;
          float4 co0 = *(const float4*)&cosP[s * 64 + dd];
          float4 co1 = *(const float4*)&cosP[s * 64 + dd + 4];
          float4 si0 = *(const float4*)&sinP[s * 64 + dd];
          float4 si1 = *(const float4*)&sinP[s * 64 + dd + 4];
          float co[8] = {co0.x, co0.y, co0.z, co0.w, co1.x, co1.y, co1.z, co1.w};
          float si[8] = {si0.x, si0.y, si0.z, si0.w, si1.x, si1.y, si1.z, si1.w};
          int lo8 = hi ? ch8 - 64 : ch8;
          float4 a0 = *(const float4*)&Trow[lo8];
          float4 a1 = *(const float4*)&Trow[lo8 + 4];
          float4 b0 = *(const float4*)&Trow[lo8 + 64];
          float4 b1 = *(const float4*)&Trow[lo8 + 68];
          float tr[8] = {a0.x, a0.y, a0.z, a0.w, a1.x, a1.y, a1.z, a1.w};
          float ti[8] = {b0.x, b0.y, b0.z, b0.w, b1.x, b1.y, b1.z, b1.w};
          float ov[8];
#pragma unroll
          for (int j = 0; j < 8; ++j)
            ov[j] = hi ? (tr[j] * si[j] + ti[j] * co[j]) : (tr[j] * co[j] - ti[j] * si[j]);
          if (isQ) {
            const float scl = 0.08838834764831845f;  // 1/sqrt(128)
            unsigned short o[8];
#pragma unroll
            for (int j = 0; j < 8; ++j) o[j] = f2bf(ov[j] * scl);
            *(uint4*)&qb[(size_t)s * HID + c] = *(const uint4*)o;
          } else {
            int ck = c - 4096, kv = ck >> 7;
            unsigned short o[8];
#pragma unroll
            for (int j = 0; j < 8; ++j) o[j] = f2bf(ov[j]);
            *(uint4*)&kb[(size_t)s * (NKV * DH) + ck] = *(const uint4*)o;
            // new_ck[0][kv][d>>3][s][d&7], chunk is 8-aligned -> contiguous 8 floats
            float* ckp = &cko[(((size_t)kv * 16 + (d >> 3)) * MAXS + s) * 8];
            *(float4*)ckp = {ov[0], ov[1], ov[2], ov[3]};
            *(float4*)(ckp + 4) = {ov[4], ov[5], ov[6], ov[7]};
          }
        } else {
          // V region: caches + compact bf16
          int cv = c - 5120, kv = cv >> 7, d = cv & 127;
          float4 a0 = *(const float4*)&Trow[ch8];
          float4 a1 = *(const float4*)&Trow[ch8 + 4];
          float* cvp = &cvo[((size_t)kv * MAXS + s) * DH + d];
          *(float4*)cvp = a0;
          *(float4*)(cvp + 4) = a1;
          float vv[8] = {a0.x, a0.y, a0.z, a0.w, a1.x, a1.y, a1.z, a1.w};
          unsigned short o[8];
#pragma unroll
          for (int j = 0; j < 8; ++j) o[j] = f2bf(vv[j]);
          *(uint4*)&vbf[(size_t)s * (NKV * DH) + cv] = *(const uint4*)o;
        }
      }
      __builtin_amdgcn_s_barrier();
    }
  }
}

// ---------------- V^T: vt[kv][d][s] from compact v_bf [s][kv*128+d] (bf16) ----------------
__global__ void k_vt_cvt(const unsigned short* __restrict__ vbf,
                         unsigned short* __restrict__ vt) {
  __shared__ unsigned short tile[32][33];
  int s0 = blockIdx.x * 32, d0 = blockIdx.y * 32, kv = blockIdx.z;
  int tx = threadIdx.x, ty = threadIdx.y;
#pragma unroll
  for (int i = 0; i < 32; i += 8)
    tile[ty + i][tx] = vbf[(size_t)(s0 + ty + i) * (NKV * DH) + kv * DH + d0 + tx];
  __syncthreads();
#pragma unroll
  for (int i = 0; i < 32; i += 8)
    vt[((size_t)kv * DH + d0 + ty + i) * SEQ + s0 + tx] = tile[tx][ty + i];
}

// ================= flash attention, paired q-tiles, double-buffered global_load_lds =================
#define SOFTMAX_TILE(T, QT, PSW)                                              \
  {                                                                           \
    if (kt == (QT)) {                                                         \
      _Pragma("unroll") for (int n = 0; n < 4; ++n) {                         \
        _Pragma("unroll") for (int r = 0; r < 4; ++r) {                       \
          int col = kv0 + n * 16 + llo;                                       \
          int row = (QT)*64 + wave * 16 + lhi * 4 + r;                        \
          if (col > row) sfr[T][n][r] = -1e9f;                                \
        }                                                                     \
      }                                                                       \
    }                                                                         \
    _Pragma("unroll") for (int r = 0; r < 4; ++r) {                           \
      float v = fmaxf(fmaxf(sfr[T][0][r], sfr[T][1][r]),                      \
                      fmaxf(sfr[T][2][r], sfr[T][3][r]));                     \
      _Pragma("unroll") for (int off = 1; off < 16; off <<= 1)                \
          v = fmaxf(v, __shfl_xor(v, off));                                   \
      float mnew = fmaxf(mrow[T][r], v);                                      \
      scl[T][r] = __expf(mrow[T][r] - mnew);                                  \
      mrow[T][r] = mnew;                                                      \
      _Pragma("unroll") for (int n = 0; n < 4; ++n) {                         \
        float e = __expf(sfr[T][n][r] - mnew);                                \
        (PSW)[(lhi * 4 + r) * 72 + n * 16 + llo] = f2bf(e);                   \
      }                                                                       \
      _Pragma("unroll") for (int dn = 0; dn < 8; ++dn)                        \
          oacc[T][dn][r] *= scl[T][r];                                        \
    }                                                                         \
  }

#define STAGEKV(KT, B)                                                                       \
  {                                                                                          \
    int _kv = (KT)*64;                                                                       \
    _Pragma("unroll") for (int c = 0; c < 4; ++c) {                                          \
      __builtin_amdgcn_global_load_lds(                                                      \
          (const __attribute__((address_space(1))) void*)(Kbase +                            \
                                                          (size_t)(_kv + c * 16) * (NKV * DH)), \
          (__attribute__((address_space(3))) void*)((char*)Ks[B] + c * 4096 + wbase), 16, 0, \
          0);                                                                                \
      __builtin_amdgcn_global_load_lds(                                                      \
          (const __attribute__((address_space(1))) void*)(Vbase + (size_t)(c * 32) * SEQ +   \
                                                          _kv),                              \
          (__attribute__((address_space(3))) void*)((char*)Vs[B] + c * 4096 + wbase), 16, 0, \
          0);                                                                                \
    }                                                                                        \
  }

__global__ __launch_bounds__(256, 2) void k_attn(const unsigned short* __restrict__ Qm,
                                                 const unsigned short* __restrict__ Km,
                                                 const unsigned short* __restrict__ Vt,
                                                 unsigned short* __restrict__ Om) {
  __shared__ unsigned short Ks[2][64 * 128];  // XOR-swizzled (chunk ^= row&15), dbuf
  __shared__ unsigned short Vs[2][128 * 64];  // XOR-swizzled (chunk ^= row&7), dbuf
  __shared__ unsigned short Ps[4][16 * 72];   // per-wave, sequentially reused P1 -> P0
  const int p = blockIdx.x, h = blockIdx.y, kvh = h >> 2;
  const int tid = threadIdx.x, wave = tid >> 6, lane = tid & 63;
  const int lhi = lane >> 4, llo = lane & 15;
  const int qt0 = p, qt1 = 31 - p;

  bf16x8 qf[2][4];
  {
    const unsigned short* q0p = Qm + (size_t)(qt0 * 64 + wave * 16 + llo) * HID + h * DH + lhi * 8;
    const unsigned short* q1p = Qm + (size_t)(qt1 * 64 + wave * 16 + llo) * HID + h * DH + lhi * 8;
#pragma unroll
    for (int f = 0; f < 4; ++f) {
      qf[0][f] = *(const bf16x8*)(q0p + f * 32);
      qf[1][f] = *(const bf16x8*)(q1p + f * 32);
    }
  }
  f32x4 oacc[2][8] = {};
  float mrow[2][4], lrow[2][4], scl[2][4];
#pragma unroll
  for (int t = 0; t < 2; ++t)
#pragma unroll
    for (int r = 0; r < 4; ++r) { mrow[t][r] = -1e30f; lrow[t][r] = 0.f; }

  bf16x8 ones;
#pragma unroll
  for (int j = 0; j < 8; ++j) ones[j] = (short)0x3F80;

  unsigned short* PsW = &Ps[wave][0];

  const int wbase = (tid & 192) * 16;
  const int chK = ((tid & 15) ^ (tid >> 4)) * 8;       // pre-swizzled K source chunk
  const int chV = ((tid & 7) ^ ((tid >> 3) & 7)) * 8;  // pre-swizzled V source chunk
  const unsigned short* Kbase = Km + (size_t)(tid >> 4) * (NKV * DH) + kvh * DH + chK;
  const unsigned short* Vbase = Vt + ((size_t)kvh * DH + (tid >> 3)) * SEQ + chV;

  STAGEKV(0, 0);
  __syncthreads();  // drains vmcnt -> tile0 in LDS

  for (int kt = 0; kt <= qt1; ++kt) {
    const int kv0 = kt * 64;
    const bool aAct = (kt <= qt0);
    const int buf = kt & 1;
    if (kt < qt1) STAGEKV(kt + 1, buf ^ 1);  // in flight across the whole compute below

    f32x4 sfr[2][4] = {};
    __builtin_amdgcn_s_setprio(1);
#pragma unroll
    for (int ks = 0; ks < 4; ++ks) {
      bf16x8 kf[4];
#pragma unroll
      for (int n = 0; n < 4; ++n)
        kf[n] = *(const bf16x8*)&Ks[buf][(n * 16 + llo) * 128 + (((ks * 4 + lhi) ^ llo) * 8)];
#pragma unroll
      for (int n = 0; n < 4; ++n)
        sfr[1][n] = __builtin_amdgcn_mfma_f32_16x16x32_bf16(qf[1][ks], kf[n], sfr[1][n], 0, 0, 0);
      if (aAct) {
#pragma unroll
        for (int n = 0; n < 4; ++n)
          sfr[0][n] = __builtin_amdgcn_mfma_f32_16x16x32_bf16(qf[0][ks], kf[n], sfr[0][n], 0, 0, 0);
      }
    }
    __builtin_amdgcn_s_setprio(0);

    // ---- tile1 softmax -> P -> frags (P buffer then reused for tile0) ----
    SOFTMAX_TILE(1, qt1, PsW);
    bf16x8 pa1a = *(const bf16x8*)&PsW[llo * 72 + lhi * 8];
    bf16x8 pa1b = *(const bf16x8*)&PsW[llo * 72 + 32 + lhi * 8];
    f32x4 ps1 = {};
    ps1 = __builtin_amdgcn_mfma_f32_16x16x32_bf16(pa1a, ones, ps1, 0, 0, 0);
    ps1 = __builtin_amdgcn_mfma_f32_16x16x32_bf16(pa1b, ones, ps1, 0, 0, 0);
#pragma unroll
    for (int r = 0; r < 4; ++r) lrow[1][r] = lrow[1][r] * scl[1][r] + ps1[r];
    bf16x8 pa0a = pa1a, pa0b = pa1b;
    if (aAct) {
      SOFTMAX_TILE(0, qt0, PsW);  // same-wave LDS in-order: safe reuse after pa1 reads
      pa0a = *(const bf16x8*)&PsW[llo * 72 + lhi * 8];
      pa0b = *(const bf16x8*)&PsW[llo * 72 + 32 + lhi * 8];
      f32x4 ps0 = {};
      ps0 = __builtin_amdgcn_mfma_f32_16x16x32_bf16(pa0a, ones, ps0, 0, 0, 0);
      ps0 = __builtin_amdgcn_mfma_f32_16x16x32_bf16(pa0b, ones, ps0, 0, 0, 0);
#pragma unroll
      for (int r = 0; r < 4; ++r) lrow[0][r] = lrow[0][r] * scl[0][r] + ps0[r];
    }

    __builtin_amdgcn_s_setprio(1);
#pragma unroll
    for (int ks2 = 0; ks2 < 2; ++ks2) {
      bf16x8 vb[8];
#pragma unroll
      for (int dn = 0; dn < 8; ++dn)
        vb[dn] = *(const bf16x8*)&Vs[buf][(dn * 16 + llo) * 64 + (((ks2 * 4 + lhi) ^ (llo & 7)) * 8)];
      bf16x8 pa1 = ks2 ? pa1b : pa1a;
#pragma unroll
      for (int dn = 0; dn < 8; ++dn)
        oacc[1][dn] = __builtin_amdgcn_mfma_f32_16x16x32_bf16(pa1, vb[dn], oacc[1][dn], 0, 0, 0);
      if (aAct) {
        bf16x8 pa0 = ks2 ? pa0b : pa0a;
#pragma unroll
        for (int dn = 0; dn < 8; ++dn)
          oacc[0][dn] = __builtin_amdgcn_mfma_f32_16x16x32_bf16(pa0, vb[dn], oacc[0][dn], 0, 0, 0);
      }
    }
    __builtin_amdgcn_s_setprio(0);

    __syncthreads();  // drains in-flight stage (had full compute to land) + read fence
  }

#pragma unroll
  for (int t = 0; t < 2; ++t) {
    const int qt = t ? qt1 : qt0;
    unsigned short* ob = Om + (size_t)(qt * 64 + wave * 16) * HID + h * DH;
#pragma unroll
    for (int dn = 0; dn < 8; ++dn)
#pragma unroll
      for (int r = 0; r < 4; ++r)
        ob[(size_t)(lhi * 4 + r) * HID + dn * 16 + llo] = f2bf(oacc[t][dn][r] / lrow[t][r]);
  }
}

extern "C" void kernel_launch(void* const* d_in, const int* in_sizes, int n_in,
                              void* d_out, int out_size, void* d_ws, size_t ws_size,
                              hipStream_t stream) {
  const float* x = (const float*)d_in[0];
  const float* cosT = (const float*)d_in[1];
  const float* sinT = (const float*)d_in[2];
  const float* wq = (const float*)d_in[4];
  const float* wk = (const float*)d_in[5];
  const float* wv = (const float*)d_in[6];
  const float* wo = (const float*)d_in[7];

  float* out = (float*)d_out;
  float* ck_out = out + (size_t)SEQ * HID;
  float* cv_out = ck_out + (size_t)MAXB * NKV * (DH / 8) * MAXS * 8;

  char* ws = (char*)d_ws;
  size_t off = 0;
  auto alloc = [&](size_t bytes) {
    char* p = ws + off;
    off += (bytes + 255) & ~(size_t)255;
    return p;
  };
  unsigned short* x_bf = (unsigned short*)alloc((size_t)SEQ * HID * 2);
  unsigned short* wqkvT = (unsigned short*)alloc((size_t)6144 * HID * 2);  // later woT
  unsigned short* q_bf = (unsigned short*)alloc((size_t)SEQ * HID * 2);
  unsigned short* k_bf = (unsigned short*)alloc((size_t)SEQ * NKV * DH * 2);
  unsigned short* v_bf = (unsigned short*)alloc((size_t)SEQ * NKV * DH * 2);
  unsigned short* v_t = (unsigned short*)alloc((size_t)NKV * DH * SEQ * 2);
  unsigned short* attn_bf = (unsigned short*)alloc((size_t)SEQ * HID * 2);
  unsigned short* woT = wqkvT;

  // 1) x -> bf16
  k_cvt_bf16<<<(SEQ * HID / 4) / 256, 256, 0, stream>>>((const float4*)x, (ushort4*)x_bf,
                                                        SEQ * HID / 4);
  // 2) fused weight transpose: [wq^T ; wk^T ; wv^T] (64x64 vectorized)
  k_transpose_cvt<<<dim3(HID / 64, HID / 64), 256, 0, stream>>>(wq, wqkvT, HID, HID);
  k_transpose_cvt<<<dim3(NKV * DH / 64, HID / 64), 256, 0, stream>>>(
      wk, wqkvT + (size_t)HID * HID, HID, NKV * DH);
  k_transpose_cvt<<<dim3(NKV * DH / 64, HID / 64), 256, 0, stream>>>(
      wv, wqkvT + (size_t)(HID + NKV * DH) * HID, HID, NKV * DH);
  // 3) fused QKV projection + RoPE + cache epilogue: grid 16x16 = 256 (full fill)
  k_gemm<1, 3, true><<<dim3(6144 / 384, SEQ / 128), 512, 0, stream>>>(
      x_bf, wqkvT, nullptr, SEQ, 6144, HID, cosT, sinT, q_bf, k_bf, ck_out, cv_out, v_bf);
  // 3b) wo^T (reuses wqkvT buffer)
  k_transpose_cvt<<<dim3(HID / 64, HID / 64), 256, 0, stream>>>(wo, woT, HID, HID);
  // 4) V^T for attention B-fragments
  k_vt_cvt<<<dim3(SEQ / 32, DH / 32, NKV), dim3(32, 8), 0, stream>>>(v_bf, v_t);
  // 5) cache tails b=1..3: reference caches are zero-initialized -> memset
  {
    const size_t slab = (size_t)NKV * (DH / 8) * MAXS * 8;  // floats (== NKV*MAXS*DH)
    hipMemsetAsync(ck_out + slab, 0, 3 * slab * sizeof(float), stream);
    hipMemsetAsync(cv_out + slab, 0, 3 * slab * sizeof(float), stream);
  }
  // 6) attention (paired q-tiles, double-buffered K/V staging)
  k_attn<<<dim3(16, NH), 256, 0, stream>>>(q_bf, k_bf, v_t, attn_bf);
  // 7) output projection: 128x256 tiles -> grid 16x16 = 256 (full fill)
  k_gemm<1, 2, false><<<dim3(HID / 256, SEQ / 128), 512, 0, stream>>>(
      attn_bf, woT, out, SEQ, HID, HID, nullptr, nullptr, nullptr, nullptr, nullptr, nullptr,
      nullptr);
}

// Round 14
// 320.715 us; speedup vs baseline: 1.0001x; 1.0001x over previous
//
#include <hip/hip_runtime.h>

typedef __attribute__((ext_vector_type(8))) short bf16x8;
typedef __attribute__((ext_vector_type(4))) float f32x4;

#define NH 32
#define NKV 8
#define DH 128
#define HID 4096
#define SEQ 2048
#define MAXB 4
#define MAXS 2048

__device__ __forceinline__ unsigned short f2bf(float f) {
  unsigned int u = __builtin_bit_cast(unsigned int, f);
  u += 0x7fffu + ((u >> 16) & 1u);
  return (unsigned short)(u >> 16);
}

// ---------------- elementwise fp32 -> bf16 ----------------
__global__ void k_cvt_bf16(const float4* __restrict__ in, ushort4* __restrict__ out, int n4) {
  int i = blockIdx.x * 256 + threadIdx.x;
  if (i >= n4) return;
  float4 v = in[i];
  ushort4 o;
  o.x = f2bf(v.x); o.y = f2bf(v.y); o.z = f2bf(v.z); o.w = f2bf(v.w);
  out[i] = o;
}

// ------------- transpose + convert: w (K x N f32) -> wt (N x K bf16), 64x64 tiles -------------
__global__ void k_transpose_cvt(const float* __restrict__ w, unsigned short* __restrict__ wt,
                                int K, int N) {
  __shared__ float T[64][65];
  const int n0 = blockIdx.x * 64, k0 = blockIdx.y * 64;
  const int t = threadIdx.x;
  const int lr = t >> 4, lc = (t & 15) * 4;
#pragma unroll
  for (int i = 0; i < 4; ++i) {
    float4 v = *(const float4*)&w[(size_t)(k0 + lr + i * 16) * N + n0 + lc];
    T[lc + 0][lr + i * 16] = v.x;
    T[lc + 1][lr + i * 16] = v.y;
    T[lc + 2][lr + i * 16] = v.z;
    T[lc + 3][lr + i * 16] = v.w;
  }
  __syncthreads();
  const int wr = t >> 3, wcol = (t & 7) * 8;
#pragma unroll
  for (int i = 0; i < 2; ++i) {
    int r = wr + i * 32;
    uint4 u;
    u.x = f2bf(T[r][wcol + 0]) | ((unsigned)f2bf(T[r][wcol + 1]) << 16);
    u.y = f2bf(T[r][wcol + 2]) | ((unsigned)f2bf(T[r][wcol + 3]) << 16);
    u.z = f2bf(T[r][wcol + 4]) | ((unsigned)f2bf(T[r][wcol + 5]) << 16);
    u.w = f2bf(T[r][wcol + 6]) | ((unsigned)f2bf(T[r][wcol + 7]) << 16);
    *(uint4*)&wt[(size_t)(n0 + r) * K + k0 + wcol] = u;
  }
}

// ============ (128*AI)x(128*BI) 2-phase-per-K-tile GEMM (T2+T3+T4+T5) ============
// Stage ledger (2 merged phases/tile, re-derived):
//   phase A: reads Ah0,Bh0,Bh1 frags | stages (t+1).Ah1 + (t+1).Bh0
//   phase B: reads Ah1 frags        | stages (t+2).Ah0 + (t+2).Bh1
// Race discipline: lgkmcnt(0) BEFORE each barrier -> every wave's LDS reads are
// complete before any wave can cross the barrier and stage into that region.
// Boundary wait once per tile (end of phase B): vmcnt(AI+BI) -> all t+1 halves
// confirmed; phase-B stages (t+2) stay in flight. Never vmcnt(0) mid-loop.
// LDS rows 64 cols (128B) as 8x16B chunks, read-swizzle chunk ^= row&7, staged
// via pre-swizzled GLOBAL source (linear LDS dest) -> 0 bank conflicts.
// FUSE variant (QKV): no C write; epilogue stages fp32 acc in LDS (2x 64-row
// passes) and emits RoPE'd Q/K (bf16), fp32 K/V caches, and compact V bf16.

#define ASHP(b, h) ((unsigned short*)smem + ((b)*2 + (h)) * (4096 * AI))
#define BSHP(b, h) ((unsigned short*)(smem + 32768 * AI) + ((b)*2 + (h)) * (4096 * BI))

#define STAGE_T(dst, srcB, rowoff, t, NI)                                                  \
  {                                                                                        \
    const unsigned short* _s = (srcB) + (size_t)(rowoff)*K + (size_t)(t) * 64;             \
    _Pragma("unroll") for (int _i = 0; _i < (NI); ++_i)                                    \
        __builtin_amdgcn_global_load_lds(                                                  \
            (const __attribute__((address_space(1))) void*)(_s + (size_t)_i * 64 * K),     \
            (__attribute__((address_space(3))) void*)((char*)(dst) + _i * 8192 + ldsW),    \
            16, 0, 0);                                                                     \
  }

#define RD_A2(bufi, h)                                                                     \
  _Pragma("unroll") for (int mf = 0; mf < MFH; ++mf) {                                     \
    af[mf][0] = *(const bf16x8*)&ASHP(bufi, h)[aRow + mf * 1024 + cOff0];                  \
    af[mf][1] = *(const bf16x8*)&ASHP(bufi, h)[aRow + mf * 1024 + cOff1];                  \
  }

#define RD_B2(bufi, h, BQ)                                                                 \
  _Pragma("unroll") for (int nf = 0; nf < NFB; ++nf) {                                     \
    BQ[nf][0] = *(const bf16x8*)&BSHP(bufi, h)[bRow + nf * 1024 + cOff0];                  \
    BQ[nf][1] = *(const bf16x8*)&BSHP(bufi, h)[bRow + nf * 1024 + cOff1];                  \
  }

#define MF_Q2(qa, qb2, BQ)                                                                 \
  _Pragma("unroll") for (int ks = 0; ks < 2; ++ks)                                         \
  _Pragma("unroll") for (int mf = 0; mf < MFH; ++mf)                                       \
  _Pragma("unroll") for (int nf = 0; nf < NFB; ++nf)                                       \
      acc[(qa)*MFH + mf][(qb2)*NFB + nf] = __builtin_amdgcn_mfma_f32_16x16x32_bf16(        \
          af[mf][ks], BQ[nf][ks], acc[(qa)*MFH + mf][(qb2)*NFB + nf], 0, 0, 0);

template <int AI, int BI, bool FUSE>
__global__ __launch_bounds__(512, 2) void k_gemm(
    const unsigned short* __restrict__ A, const unsigned short* __restrict__ BT,
    float* __restrict__ C, int M, int N, int K, const float* __restrict__ cosP,
    const float* __restrict__ sinP, unsigned short* __restrict__ qb,
    unsigned short* __restrict__ kb, float* __restrict__ cko, float* __restrict__ cvo,
    unsigned short* __restrict__ vbf) {
  constexpr int MFH = 2 * AI;  // A fragments per half per wave
  constexpr int NFB = BI;      // B fragments per half per wave
  constexpr int BM = 128 * AI, BN = 128 * BI;
  __shared__ char smem[32768 * (AI + BI)];
  const int tid = threadIdx.x;
  const int wave = tid >> 6, lane = tid & 63, lhi = lane >> 4, llo = lane & 15;
  const int wr = wave >> 2, wc = wave & 3;
  const int m0 = blockIdx.y * BM, n0 = blockIdx.x * BN;

  const int grow = tid >> 3;
  const int gc = (tid & 7) ^ (grow & 7);
  const unsigned short* Ab = A + (size_t)(m0 + grow) * K + gc * 8;
  const unsigned short* Bb = BT + (size_t)(n0 + grow) * K + gc * 8;
  const int ldsW = (tid & 448) * 16;  // wave-uniform byte base; HW adds lane*16

  const int xorc = llo & 7;
  const int cOff0 = (lhi ^ xorc) * 8;
  const int cOff1 = ((4 + lhi) ^ xorc) * 8;
  const int aRow = (wr * 32 * AI + llo) * 64;
  const int bRow = (wc * 16 * BI + llo) * 64;

  f32x4 acc[2 * MFH][2 * NFB] = {};
  bf16x8 af[MFH][2], bq0[NFB][2], bq1[NFB][2];
  const int NT = K >> 6;

  // ---- prologue: tile0 fully + tile1 {Ah0, Bh1} (the phase-B(t-1) slots) ----
  STAGE_T(ASHP(0, 0), Ab, 0, 0, AI);
  STAGE_T(BSHP(0, 0), Bb, 0, 0, BI);
  STAGE_T(BSHP(0, 1), Bb, 64 * BI, 0, BI);
  STAGE_T(ASHP(0, 1), Ab, 64 * AI, 0, AI);
  STAGE_T(ASHP(1, 0), Ab, 0, 1, AI);
  STAGE_T(BSHP(1, 1), Bb, 64 * BI, 1, BI);
  asm volatile("" ::: "memory");
  asm volatile("s_waitcnt vmcnt(%0)" ::"i"(AI + BI) : "memory");  // tile0 confirmed
  __builtin_amdgcn_s_barrier();
  asm volatile("" ::: "memory");

  for (int t = 0; t < NT; ++t) {
    const int buf = t & 1, nbuf = buf ^ 1;
    // ---- phase A: quadrants (0,0) + (0,1) ----
    RD_A2(buf, 0);
    RD_B2(buf, 0, bq0);
    RD_B2(buf, 1, bq1);
    if (t + 1 < NT) {
      STAGE_T(ASHP(nbuf, 1), Ab, 64 * AI, t + 1, AI);
      STAGE_T(BSHP(nbuf, 0), Bb, 0, t + 1, BI);
    }
    asm volatile("" ::: "memory");
    asm volatile("s_waitcnt lgkmcnt(0)" ::: "memory");  // reads done BEFORE barrier
    __builtin_amdgcn_s_barrier();
    asm volatile("" ::: "memory");
    __builtin_amdgcn_s_setprio(1);
    MF_Q2(0, 0, bq0);
    MF_Q2(0, 1, bq1);
    __builtin_amdgcn_s_setprio(0);
    // ---- phase B: quadrants (1,1) + (1,0) ----
    RD_A2(buf, 1);
    if (t + 2 < NT) {
      STAGE_T(ASHP(buf, 0), Ab, 0, t + 2, AI);
      STAGE_T(BSHP(buf, 1), Bb, 64 * BI, t + 2, BI);
    }
    asm volatile("" ::: "memory");
    if (t < NT - 2) {
      asm volatile("s_waitcnt vmcnt(%0) lgkmcnt(0)" ::"i"(AI + BI) : "memory");
    } else {
      asm volatile("s_waitcnt vmcnt(0) lgkmcnt(0)" ::: "memory");  // drain for the tail
    }
    __builtin_amdgcn_s_barrier();
    asm volatile("" ::: "memory");
    __builtin_amdgcn_s_setprio(1);
    MF_Q2(1, 1, bq1);
    MF_Q2(1, 0, bq0);
    __builtin_amdgcn_s_setprio(0);
  }

  if constexpr (!FUSE) {
    // ---- plain epilogue: C write ----
#pragma unroll
    for (int mb = 0; mb < 2; ++mb)
#pragma unroll
      for (int mf = 0; mf < MFH; ++mf)
#pragma unroll
        for (int nb = 0; nb < 2; ++nb)
#pragma unroll
          for (int nf = 0; nf < NFB; ++nf)
#pragma unroll
            for (int r = 0; r < 4; ++r)
              C[(size_t)(m0 + mb * 64 * AI + wr * 32 * AI + mf * 16 + lhi * 4 + r) * N + n0 +
                nb * 64 * BI + wc * 16 * BI + nf * 16 + llo] =
                  acc[mb * MFH + mf][nb * NFB + nf][r];
  } else {
    // ---- fused epilogue (AI=1, BN=384): RoPE + cache/operand writes ----
    // Tf: 64 x 388 fp32 tile in LDS (row stride 1552 B, 16B-aligned).
    float* Tf = (float*)smem;
#pragma unroll
    for (int p2 = 0; p2 < 2; ++p2) {
      __builtin_amdgcn_s_barrier();  // prior pass reads / K-loop reads complete
#pragma unroll
      for (int mf = 0; mf < MFH; ++mf)
#pragma unroll
        for (int nb = 0; nb < 2; ++nb)
#pragma unroll
          for (int nf = 0; nf < NFB; ++nf)
#pragma unroll
            for (int r = 0; r < 4; ++r)
              Tf[(wr * 32 + mf * 16 + lhi * 4 + r) * 388 + nb * 64 * BI + wc * 16 * BI +
                 nf * 16 + llo] = acc[p2 * MFH + mf][nb * NFB + nf][r];
      __builtin_amdgcn_s_barrier();
#pragma unroll
      for (int it = 0; it < 6; ++it) {
        int tsk = it * 512 + tid;  // 64 rows x 48 8-col chunks
        int row = tsk / 48, ch8 = (tsk % 48) * 8;
        int s = m0 + p2 * 64 + row;
        int c = n0 + ch8;
        const float* Trow = &Tf[row * 388];
        if (c < 4096 || (c >= 4096 && c < 5120)) {
          // Q or K region: RoPE
          const bool isQ = (c < 4096);
          int d = c & 127;
          const bool hi = d >= 64;
          int dd = d & 63;
          float4 co0 = *(const float4*)&cosP[s * 64 + dd];
          float4 co1 = *(const float4*)&cosP[s * 64 + dd + 4];
          float4 si0 = *(const float4*)&sinP[s * 64 + dd];
          float4 si1 = *(const float4*)&sinP[s * 64 + dd + 4];
          float co[8] = {co0.x, co0.y, co0.z, co0.w, co1.x, co1.y, co1.z, co1.w};
          float si[8] = {si0.x, si0.y, si0.z, si0.w, si1.x, si1.y, si1.z, si1.w};
          int lo8 = hi ? ch8 - 64 : ch8;
          float4 a0 = *(const float4*)&Trow[lo8];
          float4 a1 = *(const float4*)&Trow[lo8 + 4];
          float4 b0 = *(const float4*)&Trow[lo8 + 64];
          float4 b1 = *(const float4*)&Trow[lo8 + 68];
          float tr[8] = {a0.x, a0.y, a0.z, a0.w, a1.x, a1.y, a1.z, a1.w};
          float ti[8] = {b0.x, b0.y, b0.z, b0.w, b1.x, b1.y, b1.z, b1.w};
          float ov[8];
#pragma unroll
          for (int j = 0; j < 8; ++j)
            ov[j] = hi ? (tr[j] * si[j] + ti[j] * co[j]) : (tr[j] * co[j] - ti[j] * si[j]);
          if (isQ) {
            const float scl = 0.08838834764831845f;  // 1/sqrt(128)
            unsigned short o[8];
#pragma unroll
            for (int j = 0; j < 8; ++j) o[j] = f2bf(ov[j] * scl);
            *(uint4*)&qb[(size_t)s * HID + c] = *(const uint4*)o;
          } else {
            int ck = c - 4096, kv = ck >> 7;
            unsigned short o[8];
#pragma unroll
            for (int j = 0; j < 8; ++j) o[j] = f2bf(ov[j]);
            *(uint4*)&kb[(size_t)s * (NKV * DH) + ck] = *(const uint4*)o;
            // new_ck[0][kv][d>>3][s][d&7], chunk is 8-aligned -> contiguous 8 floats
            float* ckp = &cko[(((size_t)kv * 16 + (d >> 3)) * MAXS + s) * 8];
            *(float4*)ckp = {ov[0], ov[1], ov[2], ov[3]};
            *(float4*)(ckp + 4) = {ov[4], ov[5], ov[6], ov[7]};
          }
        } else {
          // V region: caches + compact bf16
          int cv = c - 5120, kv = cv >> 7, d = cv & 127;
          float4 a0 = *(const float4*)&Trow[ch8];
          float4 a1 = *(const float4*)&Trow[ch8 + 4];
          float* cvp = &cvo[((size_t)kv * MAXS + s) * DH + d];
          *(float4*)cvp = a0;
          *(float4*)(cvp + 4) = a1;
          float vv[8] = {a0.x, a0.y, a0.z, a0.w, a1.x, a1.y, a1.z, a1.w};
          unsigned short o[8];
#pragma unroll
          for (int j = 0; j < 8; ++j) o[j] = f2bf(vv[j]);
          *(uint4*)&vbf[(size_t)s * (NKV * DH) + cv] = *(const uint4*)o;
        }
      }
      __builtin_amdgcn_s_barrier();
    }
  }
}

// ---------------- V^T: vt[kv][d][s] from compact v_bf [s][kv*128+d] (bf16) ----------------
__global__ void k_vt_cvt(const unsigned short* __restrict__ vbf,
                         unsigned short* __restrict__ vt) {
  __shared__ unsigned short tile[32][33];
  int s0 = blockIdx.x * 32, d0 = blockIdx.y * 32, kv = blockIdx.z;
  int tx = threadIdx.x, ty = threadIdx.y;
#pragma unroll
  for (int i = 0; i < 32; i += 8)
    tile[ty + i][tx] = vbf[(size_t)(s0 + ty + i) * (NKV * DH) + kv * DH + d0 + tx];
  __syncthreads();
#pragma unroll
  for (int i = 0; i < 32; i += 8)
    vt[((size_t)kv * DH + d0 + ty + i) * SEQ + s0 + tx] = tile[tx][ty + i];
}

// ================= flash attention, paired q-tiles, double-buffered global_load_lds =================
#define SOFTMAX_TILE(T, QT, PSW)                                              \
  {                                                                           \
    if (kt == (QT)) {                                                         \
      _Pragma("unroll") for (int n = 0; n < 4; ++n) {                         \
        _Pragma("unroll") for (int r = 0; r < 4; ++r) {                       \
          int col = kv0 + n * 16 + llo;                                       \
          int row = (QT)*64 + wave * 16 + lhi * 4 + r;                        \
          if (col > row) sfr[T][n][r] = -1e9f;                                \
        }                                                                     \
      }                                                                       \
    }                                                                         \
    _Pragma("unroll") for (int r = 0; r < 4; ++r) {                           \
      float v = fmaxf(fmaxf(sfr[T][0][r], sfr[T][1][r]),                      \
                      fmaxf(sfr[T][2][r], sfr[T][3][r]));                     \
      _Pragma("unroll") for (int off = 1; off < 16; off <<= 1)                \
          v = fmaxf(v, __shfl_xor(v, off));                                   \
      float mnew = fmaxf(mrow[T][r], v);                                      \
      scl[T][r] = __expf(mrow[T][r] - mnew);                                  \
      mrow[T][r] = mnew;                                                      \
      _Pragma("unroll") for (int n = 0; n < 4; ++n) {                         \
        float e = __expf(sfr[T][n][r] - mnew);                                \
        (PSW)[(lhi * 4 + r) * 72 + n * 16 + llo] = f2bf(e);                   \
      }                                                                       \
      _Pragma("unroll") for (int dn = 0; dn < 8; ++dn)                        \
          oacc[T][dn][r] *= scl[T][r];                                        \
    }                                                                         \
  }

#define STAGEKV(KT, B)                                                                       \
  {                                                                                          \
    int _kv = (KT)*64;                                                                       \
    _Pragma("unroll") for (int c = 0; c < 4; ++c) {                                          \
      __builtin_amdgcn_global_load_lds(                                                      \
          (const __attribute__((address_space(1))) void*)(Kbase +                            \
                                                          (size_t)(_kv + c * 16) * (NKV * DH)), \
          (__attribute__((address_space(3))) void*)((char*)Ks[B] + c * 4096 + wbase), 16, 0, \
          0);                                                                                \
      __builtin_amdgcn_global_load_lds(                                                      \
          (const __attribute__((address_space(1))) void*)(Vbase + (size_t)(c * 32) * SEQ +   \
                                                          _kv),                              \
          (__attribute__((address_space(3))) void*)((char*)Vs[B] + c * 4096 + wbase), 16, 0, \
          0);                                                                                \
    }                                                                                        \
  }

__global__ __launch_bounds__(256, 2) void k_attn(const unsigned short* __restrict__ Qm,
                                                 const unsigned short* __restrict__ Km,
                                                 const unsigned short* __restrict__ Vt,
                                                 unsigned short* __restrict__ Om) {
  __shared__ unsigned short Ks[2][64 * 128];  // XOR-swizzled (chunk ^= row&15), dbuf
  __shared__ unsigned short Vs[2][128 * 64];  // XOR-swizzled (chunk ^= row&7), dbuf
  __shared__ unsigned short Ps[4][16 * 72];   // per-wave, sequentially reused P1 -> P0
  const int p = blockIdx.x, h = blockIdx.y, kvh = h >> 2;
  const int tid = threadIdx.x, wave = tid >> 6, lane = tid & 63;
  const int lhi = lane >> 4, llo = lane & 15;
  const int qt0 = p, qt1 = 31 - p;

  bf16x8 qf[2][4];
  {
    const unsigned short* q0p = Qm + (size_t)(qt0 * 64 + wave * 16 + llo) * HID + h * DH + lhi * 8;
    const unsigned short* q1p = Qm + (size_t)(qt1 * 64 + wave * 16 + llo) * HID + h * DH + lhi * 8;
#pragma unroll
    for (int f = 0; f < 4; ++f) {
      qf[0][f] = *(const bf16x8*)(q0p + f * 32);
      qf[1][f] = *(const bf16x8*)(q1p + f * 32);
    }
  }
  f32x4 oacc[2][8] = {};
  float mrow[2][4], lrow[2][4], scl[2][4];
#pragma unroll
  for (int t = 0; t < 2; ++t)
#pragma unroll
    for (int r = 0; r < 4; ++r) { mrow[t][r] = -1e30f; lrow[t][r] = 0.f; }

  bf16x8 ones;
#pragma unroll
  for (int j = 0; j < 8; ++j) ones[j] = (short)0x3F80;

  unsigned short* PsW = &Ps[wave][0];

  const int wbase = (tid & 192) * 16;
  const int chK = ((tid & 15) ^ (tid >> 4)) * 8;       // pre-swizzled K source chunk
  const int chV = ((tid & 7) ^ ((tid >> 3) & 7)) * 8;  // pre-swizzled V source chunk
  const unsigned short* Kbase = Km + (size_t)(tid >> 4) * (NKV * DH) + kvh * DH + chK;
  const unsigned short* Vbase = Vt + ((size_t)kvh * DH + (tid >> 3)) * SEQ + chV;

  STAGEKV(0, 0);
  __syncthreads();  // drains vmcnt -> tile0 in LDS

  for (int kt = 0; kt <= qt1; ++kt) {
    const int kv0 = kt * 64;
    const bool aAct = (kt <= qt0);
    const int buf = kt & 1;
    if (kt < qt1) STAGEKV(kt + 1, buf ^ 1);  // in flight across the whole compute below

    f32x4 sfr[2][4] = {};
    __builtin_amdgcn_s_setprio(1);
#pragma unroll
    for (int ks = 0; ks < 4; ++ks) {
      bf16x8 kf[4];
#pragma unroll
      for (int n = 0; n < 4; ++n)
        kf[n] = *(const bf16x8*)&Ks[buf][(n * 16 + llo) * 128 + (((ks * 4 + lhi) ^ llo) * 8)];
#pragma unroll
      for (int n = 0; n < 4; ++n)
        sfr[1][n] = __builtin_amdgcn_mfma_f32_16x16x32_bf16(qf[1][ks], kf[n], sfr[1][n], 0, 0, 0);
      if (aAct) {
#pragma unroll
        for (int n = 0; n < 4; ++n)
          sfr[0][n] = __builtin_amdgcn_mfma_f32_16x16x32_bf16(qf[0][ks], kf[n], sfr[0][n], 0, 0, 0);
      }
    }
    __builtin_amdgcn_s_setprio(0);

    // ---- tile1 softmax -> P -> frags (P buffer then reused for tile0) ----
    SOFTMAX_TILE(1, qt1, PsW);
    bf16x8 pa1a = *(const bf16x8*)&PsW[llo * 72 + lhi * 8];
    bf16x8 pa1b = *(const bf16x8*)&PsW[llo * 72 + 32 + lhi * 8];
    f32x4 ps1 = {};
    ps1 = __builtin_amdgcn_mfma_f32_16x16x32_bf16(pa1a, ones, ps1, 0, 0, 0);
    ps1 = __builtin_amdgcn_mfma_f32_16x16x32_bf16(pa1b, ones, ps1, 0, 0, 0);
#pragma unroll
    for (int r = 0; r < 4; ++r) lrow[1][r] = lrow[1][r] * scl[1][r] + ps1[r];
    bf16x8 pa0a = pa1a, pa0b = pa1b;
    if (aAct) {
      SOFTMAX_TILE(0, qt0, PsW);  // same-wave LDS in-order: safe reuse after pa1 reads
      pa0a = *(const bf16x8*)&PsW[llo * 72 + lhi * 8];
      pa0b = *(const bf16x8*)&PsW[llo * 72 + 32 + lhi * 8];
      f32x4 ps0 = {};
      ps0 = __builtin_amdgcn_mfma_f32_16x16x32_bf16(pa0a, ones, ps0, 0, 0, 0);
      ps0 = __builtin_amdgcn_mfma_f32_16x16x32_bf16(pa0b, ones, ps0, 0, 0, 0);
#pragma unroll
      for (int r = 0; r < 4; ++r) lrow[0][r] = lrow[0][r] * scl[0][r] + ps0[r];
    }

    __builtin_amdgcn_s_setprio(1);
#pragma unroll
    for (int ks2 = 0; ks2 < 2; ++ks2) {
      bf16x8 vb[8];
#pragma unroll
      for (int dn = 0; dn < 8; ++dn)
        vb[dn] = *(const bf16x8*)&Vs[buf][(dn * 16 + llo) * 64 + (((ks2 * 4 + lhi) ^ (llo & 7)) * 8)];
      bf16x8 pa1 = ks2 ? pa1b : pa1a;
#pragma unroll
      for (int dn = 0; dn < 8; ++dn)
        oacc[1][dn] = __builtin_amdgcn_mfma_f32_16x16x32_bf16(pa1, vb[dn], oacc[1][dn], 0, 0, 0);
      if (aAct) {
        bf16x8 pa0 = ks2 ? pa0b : pa0a;
#pragma unroll
        for (int dn = 0; dn < 8; ++dn)
          oacc[0][dn] = __builtin_amdgcn_mfma_f32_16x16x32_bf16(pa0, vb[dn], oacc[0][dn], 0, 0, 0);
      }
    }
    __builtin_amdgcn_s_setprio(0);

    __syncthreads();  // drains in-flight stage (had full compute to land) + read fence
  }

#pragma unroll
  for (int t = 0; t < 2; ++t) {
    const int qt = t ? qt1 : qt0;
    unsigned short* ob = Om + (size_t)(qt * 64 + wave * 16) * HID + h * DH;
#pragma unroll
    for (int dn = 0; dn < 8; ++dn)
#pragma unroll
      for (int r = 0; r < 4; ++r)
        ob[(size_t)(lhi * 4 + r) * HID + dn * 16 + llo] = f2bf(oacc[t][dn][r] / lrow[t][r]);
  }
}

extern "C" void kernel_launch(void* const* d_in, const int* in_sizes, int n_in,
                              void* d_out, int out_size, void* d_ws, size_t ws_size,
                              hipStream_t stream) {
  const float* x = (const float*)d_in[0];
  const float* cosT = (const float*)d_in[1];
  const float* sinT = (const float*)d_in[2];
  const float* wq = (const float*)d_in[4];
  const float* wk = (const float*)d_in[5];
  const float* wv = (const float*)d_in[6];
  const float* wo = (const float*)d_in[7];

  float* out = (float*)d_out;
  float* ck_out = out + (size_t)SEQ * HID;
  float* cv_out = ck_out + (size_t)MAXB * NKV * (DH / 8) * MAXS * 8;

  char* ws = (char*)d_ws;
  size_t off = 0;
  auto alloc = [&](size_t bytes) {
    char* p = ws + off;
    off += (bytes + 255) & ~(size_t)255;
    return p;
  };
  unsigned short* x_bf = (unsigned short*)alloc((size_t)SEQ * HID * 2);
  unsigned short* wqkvT = (unsigned short*)alloc((size_t)6144 * HID * 2);  // later woT
  unsigned short* q_bf = (unsigned short*)alloc((size_t)SEQ * HID * 2);
  unsigned short* k_bf = (unsigned short*)alloc((size_t)SEQ * NKV * DH * 2);
  unsigned short* v_bf = (unsigned short*)alloc((size_t)SEQ * NKV * DH * 2);
  unsigned short* v_t = (unsigned short*)alloc((size_t)NKV * DH * SEQ * 2);
  unsigned short* attn_bf = (unsigned short*)alloc((size_t)SEQ * HID * 2);
  unsigned short* woT = wqkvT;

  // 1) x -> bf16
  k_cvt_bf16<<<(SEQ * HID / 4) / 256, 256, 0, stream>>>((const float4*)x, (ushort4*)x_bf,
                                                        SEQ * HID / 4);
  // 2) fused weight transpose: [wq^T ; wk^T ; wv^T] (64x64 vectorized)
  k_transpose_cvt<<<dim3(HID / 64, HID / 64), 256, 0, stream>>>(wq, wqkvT, HID, HID);
  k_transpose_cvt<<<dim3(NKV * DH / 64, HID / 64), 256, 0, stream>>>(
      wk, wqkvT + (size_t)HID * HID, HID, NKV * DH);
  k_transpose_cvt<<<dim3(NKV * DH / 64, HID / 64), 256, 0, stream>>>(
      wv, wqkvT + (size_t)(HID + NKV * DH) * HID, HID, NKV * DH);
  // 3) fused QKV projection + RoPE + cache epilogue: grid 16x16 = 256 (full fill)
  k_gemm<1, 3, true><<<dim3(6144 / 384, SEQ / 128), 512, 0, stream>>>(
      x_bf, wqkvT, nullptr, SEQ, 6144, HID, cosT, sinT, q_bf, k_bf, ck_out, cv_out, v_bf);
  // 3b) wo^T (reuses wqkvT buffer)
  k_transpose_cvt<<<dim3(HID / 64, HID / 64), 256, 0, stream>>>(wo, woT, HID, HID);
  // 4) V^T for attention B-fragments
  k_vt_cvt<<<dim3(SEQ / 32, DH / 32, NKV), dim3(32, 8), 0, stream>>>(v_bf, v_t);
  // 5) cache tails b=1..3: reference caches are zero-initialized -> memset
  {
    const size_t slab = (size_t)NKV * (DH / 8) * MAXS * 8;  // floats (== NKV*MAXS*DH)
    hipMemsetAsync(ck_out + slab, 0, 3 * slab * sizeof(float), stream);
    hipMemsetAsync(cv_out + slab, 0, 3 * slab * sizeof(float), stream);
  }
  // 6) attention (paired q-tiles, double-buffered K/V staging)
  k_attn<<<dim3(16, NH), 256, 0, stream>>>(q_bf, k_bf, v_t, attn_bf);
  // 7) output projection: 128x256 tiles -> grid 16x16 = 256 (full fill)
  k_gemm<1, 2, false><<<dim3(HID / 256, SEQ / 128), 512, 0, stream>>>(
      attn_bf, woT, out, SEQ, HID, HID, nullptr, nullptr, nullptr, nullptr, nullptr, nullptr,
      nullptr);
}

// Round 15
// 319.572 us; speedup vs baseline: 1.0037x; 1.0036x over previous
//
#include <hip/hip_runtime.h>

typedef __attribute__((ext_vector_type(8))) short bf16x8;
typedef __attribute__((ext_vector_type(4))) float f32x4;

#define NH 32
#define NKV 8
#define DH 128
#define HID 4096
#define SEQ 2048
#define MAXB 4
#define MAXS 2048

__device__ __forceinline__ unsigned short f2bf(float f) {
  unsigned int u = __builtin_bit_cast(unsigned int, f);
  u += 0x7fffu + ((u >> 16) & 1u);
  return (unsigned short)(u >> 16);
}

// ---------------- elementwise fp32 -> bf16 ----------------
__global__ void k_cvt_bf16(const float4* __restrict__ in, ushort4* __restrict__ out, int n4) {
  int i = blockIdx.x * 256 + threadIdx.x;
  if (i >= n4) return;
  float4 v = in[i];
  ushort4 o;
  o.x = f2bf(v.x); o.y = f2bf(v.y); o.z = f2bf(v.z); o.w = f2bf(v.w);
  out[i] = o;
}

// ------------- all weight transposes in one launch: w (K x N f32) -> wt (N x K bf16) -------------
// z: 0=wq, 1=wk, 2=wv (into wqkvT rows 0/4096/5120), 3=wo (into woT). K=HID for all.
__global__ void k_transpose_all(const float* __restrict__ wq, const float* __restrict__ wk,
                                const float* __restrict__ wv, const float* __restrict__ wo,
                                unsigned short* __restrict__ wqkvT,
                                unsigned short* __restrict__ woT) {
  const int z = blockIdx.z;
  const float* src;
  unsigned short* dst;
  int N;
  if (z == 0) { src = wq; dst = wqkvT; N = HID; }
  else if (z == 1) { src = wk; dst = wqkvT + (size_t)HID * HID; N = NKV * DH; }
  else if (z == 2) { src = wv; dst = wqkvT + (size_t)(HID + NKV * DH) * HID; N = NKV * DH; }
  else { src = wo; dst = woT; N = HID; }
  const int n0 = blockIdx.x * 64, k0 = blockIdx.y * 64;
  if (n0 >= N) return;
  __shared__ float T[64][65];
  const int t = threadIdx.x;
  const int lr = t >> 4, lc = (t & 15) * 4;
#pragma unroll
  for (int i = 0; i < 4; ++i) {
    float4 v = *(const float4*)&src[(size_t)(k0 + lr + i * 16) * N + n0 + lc];
    T[lc + 0][lr + i * 16] = v.x;
    T[lc + 1][lr + i * 16] = v.y;
    T[lc + 2][lr + i * 16] = v.z;
    T[lc + 3][lr + i * 16] = v.w;
  }
  __syncthreads();
  const int wr = t >> 3, wcol = (t & 7) * 8;
#pragma unroll
  for (int i = 0; i < 2; ++i) {
    int r = wr + i * 32;
    uint4 u;
    u.x = f2bf(T[r][wcol + 0]) | ((unsigned)f2bf(T[r][wcol + 1]) << 16);
    u.y = f2bf(T[r][wcol + 2]) | ((unsigned)f2bf(T[r][wcol + 3]) << 16);
    u.z = f2bf(T[r][wcol + 4]) | ((unsigned)f2bf(T[r][wcol + 5]) << 16);
    u.w = f2bf(T[r][wcol + 6]) | ((unsigned)f2bf(T[r][wcol + 7]) << 16);
    *(uint4*)&dst[(size_t)(n0 + r) * HID + k0 + wcol] = u;
  }
}

// ============ (128*AI)x(128*BI) 2-phase-per-K-tile GEMM (T2+T3+T4+T5) ============
// Stage ledger (2 merged phases/tile):
//   phase A: reads Ah0,Bh0,Bh1 frags | stages (t+1).Ah1 + (t+1).Bh0
//   phase B: reads Ah1 frags        | stages (t+2).Ah0 + (t+2).Bh1
// Race discipline: lgkmcnt(0) BEFORE each barrier. Boundary wait once per tile
// (end of phase B): vmcnt(AI+BI). Never vmcnt(0) mid-loop.
// LDS rows 64 cols (128B) as 8x16B chunks, read-swizzle chunk ^= row&7, staged
// via pre-swizzled GLOBAL source (linear LDS dest) -> ~0 bank conflicts.
// <1,1> (64KB LDS) runs 2 blocks/CU -> cross-block MFMA/read overlap.
// FUSE variant (QKV): epilogue emits RoPE'd Q/K (bf16), fp32 caches, compact V.

#define ASHP(b, h) ((unsigned short*)smem + ((b)*2 + (h)) * (4096 * AI))
#define BSHP(b, h) ((unsigned short*)(smem + 32768 * AI) + ((b)*2 + (h)) * (4096 * BI))

#define STAGE_T(dst, srcB, rowoff, t, NI)                                                  \
  {                                                                                        \
    const unsigned short* _s = (srcB) + (size_t)(rowoff)*K + (size_t)(t) * 64;             \
    _Pragma("unroll") for (int _i = 0; _i < (NI); ++_i)                                    \
        __builtin_amdgcn_global_load_lds(                                                  \
            (const __attribute__((address_space(1))) void*)(_s + (size_t)_i * 64 * K),     \
            (__attribute__((address_space(3))) void*)((char*)(dst) + _i * 8192 + ldsW),    \
            16, 0, 0);                                                                     \
  }

#define RD_A2(bufi, h)                                                                     \
  _Pragma("unroll") for (int mf = 0; mf < MFH; ++mf) {                                     \
    af[mf][0] = *(const bf16x8*)&ASHP(bufi, h)[aRow + mf * 1024 + cOff0];                  \
    af[mf][1] = *(const bf16x8*)&ASHP(bufi, h)[aRow + mf * 1024 + cOff1];                  \
  }

#define RD_B2(bufi, h, BQ)                                                                 \
  _Pragma("unroll") for (int nf = 0; nf < NFB; ++nf) {                                     \
    BQ[nf][0] = *(const bf16x8*)&BSHP(bufi, h)[bRow + nf * 1024 + cOff0];                  \
    BQ[nf][1] = *(const bf16x8*)&BSHP(bufi, h)[bRow + nf * 1024 + cOff1];                  \
  }

#define MF_Q2(qa, qb2, BQ)                                                                 \
  _Pragma("unroll") for (int ks = 0; ks < 2; ++ks)                                         \
  _Pragma("unroll") for (int mf = 0; mf < MFH; ++mf)                                       \
  _Pragma("unroll") for (int nf = 0; nf < NFB; ++nf)                                       \
      acc[(qa)*MFH + mf][(qb2)*NFB + nf] = __builtin_amdgcn_mfma_f32_16x16x32_bf16(        \
          af[mf][ks], BQ[nf][ks], acc[(qa)*MFH + mf][(qb2)*NFB + nf], 0, 0, 0);

template <int AI, int BI, bool FUSE>
__global__ __launch_bounds__(512, 2) void k_gemm(
    const unsigned short* __restrict__ A, const unsigned short* __restrict__ BT,
    float* __restrict__ C, int M, int N, int K, const float* __restrict__ cosP,
    const float* __restrict__ sinP, unsigned short* __restrict__ qb,
    unsigned short* __restrict__ kb, float* __restrict__ cko, float* __restrict__ cvo,
    unsigned short* __restrict__ vbf) {
  constexpr int MFH = 2 * AI;  // A fragments per half per wave
  constexpr int NFB = BI;      // B fragments per half per wave
  constexpr int BM = 128 * AI, BN = 128 * BI;
  __shared__ char smem[32768 * (AI + BI)];
  const int tid = threadIdx.x;
  const int wave = tid >> 6, lane = tid & 63, lhi = lane >> 4, llo = lane & 15;
  const int wr = wave >> 2, wc = wave & 3;
  const int m0 = blockIdx.y * BM, n0 = blockIdx.x * BN;

  const int grow = tid >> 3;
  const int gc = (tid & 7) ^ (grow & 7);
  const unsigned short* Ab = A + (size_t)(m0 + grow) * K + gc * 8;
  const unsigned short* Bb = BT + (size_t)(n0 + grow) * K + gc * 8;
  const int ldsW = (tid & 448) * 16;  // wave-uniform byte base; HW adds lane*16

  const int xorc = llo & 7;
  const int cOff0 = (lhi ^ xorc) * 8;
  const int cOff1 = ((4 + lhi) ^ xorc) * 8;
  const int aRow = (wr * 32 * AI + llo) * 64;
  const int bRow = (wc * 16 * BI + llo) * 64;

  f32x4 acc[2 * MFH][2 * NFB] = {};
  bf16x8 af[MFH][2], bq0[NFB][2], bq1[NFB][2];
  const int NT = K >> 6;

  // ---- prologue: tile0 fully + tile1 {Ah0, Bh1} (the phase-B(t-1) slots) ----
  STAGE_T(ASHP(0, 0), Ab, 0, 0, AI);
  STAGE_T(BSHP(0, 0), Bb, 0, 0, BI);
  STAGE_T(BSHP(0, 1), Bb, 64 * BI, 0, BI);
  STAGE_T(ASHP(0, 1), Ab, 64 * AI, 0, AI);
  STAGE_T(ASHP(1, 0), Ab, 0, 1, AI);
  STAGE_T(BSHP(1, 1), Bb, 64 * BI, 1, BI);
  asm volatile("" ::: "memory");
  asm volatile("s_waitcnt vmcnt(%0)" ::"i"(AI + BI) : "memory");  // tile0 confirmed
  __builtin_amdgcn_s_barrier();
  asm volatile("" ::: "memory");

  for (int t = 0; t < NT; ++t) {
    const int buf = t & 1, nbuf = buf ^ 1;
    // ---- phase A: quadrants (0,0) + (0,1) ----
    RD_A2(buf, 0);
    RD_B2(buf, 0, bq0);
    RD_B2(buf, 1, bq1);
    if (t + 1 < NT) {
      STAGE_T(ASHP(nbuf, 1), Ab, 64 * AI, t + 1, AI);
      STAGE_T(BSHP(nbuf, 0), Bb, 0, t + 1, BI);
    }
    asm volatile("" ::: "memory");
    asm volatile("s_waitcnt lgkmcnt(0)" ::: "memory");  // reads done BEFORE barrier
    __builtin_amdgcn_s_barrier();
    asm volatile("" ::: "memory");
    __builtin_amdgcn_s_setprio(1);
    MF_Q2(0, 0, bq0);
    MF_Q2(0, 1, bq1);
    __builtin_amdgcn_s_setprio(0);
    // ---- phase B: quadrants (1,1) + (1,0) ----
    RD_A2(buf, 1);
    if (t + 2 < NT) {
      STAGE_T(ASHP(buf, 0), Ab, 0, t + 2, AI);
      STAGE_T(BSHP(buf, 1), Bb, 64 * BI, t + 2, BI);
    }
    asm volatile("" ::: "memory");
    if (t < NT - 2) {
      asm volatile("s_waitcnt vmcnt(%0) lgkmcnt(0)" ::"i"(AI + BI) : "memory");
    } else {
      asm volatile("s_waitcnt vmcnt(0) lgkmcnt(0)" ::: "memory");  // drain for the tail
    }
    __builtin_amdgcn_s_barrier();
    asm volatile("" ::: "memory");
    __builtin_amdgcn_s_setprio(1);
    MF_Q2(1, 1, bq1);
    MF_Q2(1, 0, bq0);
    __builtin_amdgcn_s_setprio(0);
  }

  if constexpr (!FUSE) {
    // ---- plain epilogue: C write ----
#pragma unroll
    for (int mb = 0; mb < 2; ++mb)
#pragma unroll
      for (int mf = 0; mf < MFH; ++mf)
#pragma unroll
        for (int nb = 0; nb < 2; ++nb)
#pragma unroll
          for (int nf = 0; nf < NFB; ++nf)
#pragma unroll
            for (int r = 0; r < 4; ++r)
              C[(size_t)(m0 + mb * 64 * AI + wr * 32 * AI + mf * 16 + lhi * 4 + r) * N + n0 +
                nb * 64 * BI + wc * 16 * BI + nf * 16 + llo] =
                  acc[mb * MFH + mf][nb * NFB + nf][r];
  } else {
    // ---- fused epilogue (AI=1, BN=384): RoPE + cache/operand writes ----
    // Tf: 64 x 388 fp32 tile in LDS (row stride 1552 B, 16B-aligned).
    float* Tf = (float*)smem;
#pragma unroll
    for (int p2 = 0; p2 < 2; ++p2) {
      __builtin_amdgcn_s_barrier();  // prior pass reads / K-loop reads complete
#pragma unroll
      for (int mf = 0; mf < MFH; ++mf)
#pragma unroll
        for (int nb = 0; nb < 2; ++nb)
#pragma unroll
          for (int nf = 0; nf < NFB; ++nf)
#pragma unroll
            for (int r = 0; r < 4; ++r)
              Tf[(wr * 32 + mf * 16 + lhi * 4 + r) * 388 + nb * 64 * BI + wc * 16 * BI +
                 nf * 16 + llo] = acc[p2 * MFH + mf][nb * NFB + nf][r];
      __builtin_amdgcn_s_barrier();
#pragma unroll
      for (int it = 0; it < 6; ++it) {
        int tsk = it * 512 + tid;  // 64 rows x 48 8-col chunks
        int row = tsk / 48, ch8 = (tsk % 48) * 8;
        int s = m0 + p2 * 64 + row;
        int c = n0 + ch8;
        const float* Trow = &Tf[row * 388];
        if (c < 4096 || (c >= 4096 && c < 5120)) {
          // Q or K region: RoPE
          const bool isQ = (c < 4096);
          int d = c & 127;
          const bool hi = d >= 64;
          int dd = d & 63;
          float4 co0 = *(const float4*)&cosP[s * 64 + dd];
          float4 co1 = *(const float4*)&cosP[s * 64 + dd + 4];
          float4 si0 = *(const float4*)&sinP[s * 64 + dd];
          float4 si1 = *(const float4*)&sinP[s * 64 + dd + 4];
          float co[8] = {co0.x, co0.y, co0.z, co0.w, co1.x, co1.y, co1.z, co1.w};
          float si[8] = {si0.x, si0.y, si0.z, si0.w, si1.x, si1.y, si1.z, si1.w};
          int lo8 = hi ? ch8 - 64 : ch8;
          float4 a0 = *(const float4*)&Trow[lo8];
          float4 a1 = *(const float4*)&Trow[lo8 + 4];
          float4 b0 = *(const float4*)&Trow[lo8 + 64];
          float4 b1 = *(const float4*)&Trow[lo8 + 68];
          float tr[8] = {a0.x, a0.y, a0.z, a0.w, a1.x, a1.y, a1.z, a1.w};
          float ti[8] = {b0.x, b0.y, b0.z, b0.w, b1.x, b1.y, b1.z, b1.w};
          float ov[8];
#pragma unroll
          for (int j = 0; j < 8; ++j)
            ov[j] = hi ? (tr[j] * si[j] + ti[j] * co[j]) : (tr[j] * co[j] - ti[j] * si[j]);
          if (isQ) {
            const float scl = 0.08838834764831845f;  // 1/sqrt(128)
            unsigned short o[8];
#pragma unroll
            for (int j = 0; j < 8; ++j) o[j] = f2bf(ov[j] * scl);
            *(uint4*)&qb[(size_t)s * HID + c] = *(const uint4*)o;
          } else {
            int ck = c - 4096, kv = ck >> 7;
            unsigned short o[8];
#pragma unroll
            for (int j = 0; j < 8; ++j) o[j] = f2bf(ov[j]);
            *(uint4*)&kb[(size_t)s * (NKV * DH) + ck] = *(const uint4*)o;
            // new_ck[0][kv][d>>3][s][d&7], chunk is 8-aligned -> contiguous 8 floats
            float* ckp = &cko[(((size_t)kv * 16 + (d >> 3)) * MAXS + s) * 8];
            *(float4*)ckp = {ov[0], ov[1], ov[2], ov[3]};
            *(float4*)(ckp + 4) = {ov[4], ov[5], ov[6], ov[7]};
          }
        } else {
          // V region: caches + compact bf16
          int cv = c - 5120, kv = cv >> 7, d = cv & 127;
          float4 a0 = *(const float4*)&Trow[ch8];
          float4 a1 = *(const float4*)&Trow[ch8 + 4];
          float* cvp = &cvo[((size_t)kv * MAXS + s) * DH + d];
          *(float4*)cvp = a0;
          *(float4*)(cvp + 4) = a1;
          float vv[8] = {a0.x, a0.y, a0.z, a0.w, a1.x, a1.y, a1.z, a1.w};
          unsigned short o[8];
#pragma unroll
          for (int j = 0; j < 8; ++j) o[j] = f2bf(vv[j]);
          *(uint4*)&vbf[(size_t)s * (NKV * DH) + cv] = *(const uint4*)o;
        }
      }
      __builtin_amdgcn_s_barrier();
    }
  }
}

// ---------------- V^T: vt[kv][d][s] from compact v_bf [s][kv*128+d] (bf16) ----------------
__global__ void k_vt_cvt(const unsigned short* __restrict__ vbf,
                         unsigned short* __restrict__ vt) {
  __shared__ unsigned short tile[32][33];
  int s0 = blockIdx.x * 32, d0 = blockIdx.y * 32, kv = blockIdx.z;
  int tx = threadIdx.x, ty = threadIdx.y;
#pragma unroll
  for (int i = 0; i < 32; i += 8)
    tile[ty + i][tx] = vbf[(size_t)(s0 + ty + i) * (NKV * DH) + kv * DH + d0 + tx];
  __syncthreads();
#pragma unroll
  for (int i = 0; i < 32; i += 8)
    vt[((size_t)kv * DH + d0 + ty + i) * SEQ + s0 + tx] = tile[tx][ty + i];
}

// ================= flash attention, paired q-tiles, double-buffered global_load_lds =================
#define SOFTMAX_TILE(T, QT, PSW)                                              \
  {                                                                           \
    if (kt == (QT)) {                                                         \
      _Pragma("unroll") for (int n = 0; n < 4; ++n) {                         \
        _Pragma("unroll") for (int r = 0; r < 4; ++r) {                       \
          int col = kv0 + n * 16 + llo;                                       \
          int row = (QT)*64 + wave * 16 + lhi * 4 + r;                        \
          if (col > row) sfr[T][n][r] = -1e9f;                                \
        }                                                                     \
      }                                                                       \
    }                                                                         \
    _Pragma("unroll") for (int r = 0; r < 4; ++r) {                           \
      float v = fmaxf(fmaxf(sfr[T][0][r], sfr[T][1][r]),                      \
                      fmaxf(sfr[T][2][r], sfr[T][3][r]));                     \
      _Pragma("unroll") for (int off = 1; off < 16; off <<= 1)                \
          v = fmaxf(v, __shfl_xor(v, off));                                   \
      float mnew = fmaxf(mrow[T][r], v);                                      \
      scl[T][r] = __expf(mrow[T][r] - mnew);                                  \
      mrow[T][r] = mnew;                                                      \
      _Pragma("unroll") for (int n = 0; n < 4; ++n) {                         \
        float e = __expf(sfr[T][n][r] - mnew);                                \
        (PSW)[(lhi * 4 + r) * 72 + n * 16 + llo] = f2bf(e);                   \
      }                                                                       \
      _Pragma("unroll") for (int dn = 0; dn < 8; ++dn)                        \
          oacc[T][dn][r] *= scl[T][r];                                        \
    }                                                                         \
  }

#define STAGEKV(KT, B)                                                                       \
  {                                                                                          \
    int _kv = (KT)*64;                                                                       \
    _Pragma("unroll") for (int c = 0; c < 4; ++c) {                                          \
      __builtin_amdgcn_global_load_lds(                                                      \
          (const __attribute__((address_space(1))) void*)(Kbase +                            \
                                                          (size_t)(_kv + c * 16) * (NKV * DH)), \
          (__attribute__((address_space(3))) void*)((char*)Ks[B] + c * 4096 + wbase), 16, 0, \
          0);                                                                                \
      __builtin_amdgcn_global_load_lds(                                                      \
          (const __attribute__((address_space(1))) void*)(Vbase + (size_t)(c * 32) * SEQ +   \
                                                          _kv),                              \
          (__attribute__((address_space(3))) void*)((char*)Vs[B] + c * 4096 + wbase), 16, 0, \
          0);                                                                                \
    }                                                                                        \
  }

__global__ __launch_bounds__(256, 2) void k_attn(const unsigned short* __restrict__ Qm,
                                                 const unsigned short* __restrict__ Km,
                                                 const unsigned short* __restrict__ Vt,
                                                 unsigned short* __restrict__ Om) {
  __shared__ unsigned short Ks[2][64 * 128];  // XOR-swizzled (chunk ^= row&15), dbuf
  __shared__ unsigned short Vs[2][128 * 64];  // XOR-swizzled (chunk ^= row&7), dbuf
  __shared__ unsigned short Ps[4][16 * 72];   // per-wave, sequentially reused P1 -> P0
  const int p = blockIdx.x, h = blockIdx.y, kvh = h >> 2;
  const int tid = threadIdx.x, wave = tid >> 6, lane = tid & 63;
  const int lhi = lane >> 4, llo = lane & 15;
  const int qt0 = p, qt1 = 31 - p;

  bf16x8 qf[2][4];
  {
    const unsigned short* q0p = Qm + (size_t)(qt0 * 64 + wave * 16 + llo) * HID + h * DH + lhi * 8;
    const unsigned short* q1p = Qm + (size_t)(qt1 * 64 + wave * 16 + llo) * HID + h * DH + lhi * 8;
#pragma unroll
    for (int f = 0; f < 4; ++f) {
      qf[0][f] = *(const bf16x8*)(q0p + f * 32);
      qf[1][f] = *(const bf16x8*)(q1p + f * 32);
    }
  }
  f32x4 oacc[2][8] = {};
  float mrow[2][4], lrow[2][4], scl[2][4];
#pragma unroll
  for (int t = 0; t < 2; ++t)
#pragma unroll
    for (int r = 0; r < 4; ++r) { mrow[t][r] = -1e30f; lrow[t][r] = 0.f; }

  bf16x8 ones;
#pragma unroll
  for (int j = 0; j < 8; ++j) ones[j] = (short)0x3F80;

  unsigned short* PsW = &Ps[wave][0];

  const int wbase = (tid & 192) * 16;
  const int chK = ((tid & 15) ^ (tid >> 4)) * 8;       // pre-swizzled K source chunk
  const int chV = ((tid & 7) ^ ((tid >> 3) & 7)) * 8;  // pre-swizzled V source chunk
  const unsigned short* Kbase = Km + (size_t)(tid >> 4) * (NKV * DH) + kvh * DH + chK;
  const unsigned short* Vbase = Vt + ((size_t)kvh * DH + (tid >> 3)) * SEQ + chV;

  STAGEKV(0, 0);
  __syncthreads();  // drains vmcnt -> tile0 in LDS

  for (int kt = 0; kt <= qt1; ++kt) {
    const int kv0 = kt * 64;
    const bool aAct = (kt <= qt0);
    const int buf = kt & 1;
    if (kt < qt1) STAGEKV(kt + 1, buf ^ 1);  // in flight across the whole compute below

    f32x4 sfr[2][4] = {};
    __builtin_amdgcn_s_setprio(1);
#pragma unroll
    for (int ks = 0; ks < 4; ++ks) {
      bf16x8 kf[4];
#pragma unroll
      for (int n = 0; n < 4; ++n)
        kf[n] = *(const bf16x8*)&Ks[buf][(n * 16 + llo) * 128 + (((ks * 4 + lhi) ^ llo) * 8)];
#pragma unroll
      for (int n = 0; n < 4; ++n)
        sfr[1][n] = __builtin_amdgcn_mfma_f32_16x16x32_bf16(qf[1][ks], kf[n], sfr[1][n], 0, 0, 0);
      if (aAct) {
#pragma unroll
        for (int n = 0; n < 4; ++n)
          sfr[0][n] = __builtin_amdgcn_mfma_f32_16x16x32_bf16(qf[0][ks], kf[n], sfr[0][n], 0, 0, 0);
      }
    }
    __builtin_amdgcn_s_setprio(0);

    // ---- tile1 softmax -> P -> frags (P buffer then reused for tile0) ----
    SOFTMAX_TILE(1, qt1, PsW);
    bf16x8 pa1a = *(const bf16x8*)&PsW[llo * 72 + lhi * 8];
    bf16x8 pa1b = *(const bf16x8*)&PsW[llo * 72 + 32 + lhi * 8];
    f32x4 ps1 = {};
    ps1 = __builtin_amdgcn_mfma_f32_16x16x32_bf16(pa1a, ones, ps1, 0, 0, 0);
    ps1 = __builtin_amdgcn_mfma_f32_16x16x32_bf16(pa1b, ones, ps1, 0, 0, 0);
#pragma unroll
    for (int r = 0; r < 4; ++r) lrow[1][r] = lrow[1][r] * scl[1][r] + ps1[r];
    bf16x8 pa0a = pa1a, pa0b = pa1b;
    if (aAct) {
      SOFTMAX_TILE(0, qt0, PsW);  // same-wave LDS in-order: safe reuse after pa1 reads
      pa0a = *(const bf16x8*)&PsW[llo * 72 + lhi * 8];
      pa0b = *(const bf16x8*)&PsW[llo * 72 + 32 + lhi * 8];
      f32x4 ps0 = {};
      ps0 = __builtin_amdgcn_mfma_f32_16x16x32_bf16(pa0a, ones, ps0, 0, 0, 0);
      ps0 = __builtin_amdgcn_mfma_f32_16x16x32_bf16(pa0b, ones, ps0, 0, 0, 0);
#pragma unroll
      for (int r = 0; r < 4; ++r) lrow[0][r] = lrow[0][r] * scl[0][r] + ps0[r];
    }

    __builtin_amdgcn_s_setprio(1);
#pragma unroll
    for (int ks2 = 0; ks2 < 2; ++ks2) {
      bf16x8 vb[8];
#pragma unroll
      for (int dn = 0; dn < 8; ++dn)
        vb[dn] = *(const bf16x8*)&Vs[buf][(dn * 16 + llo) * 64 + (((ks2 * 4 + lhi) ^ (llo & 7)) * 8)];
      bf16x8 pa1 = ks2 ? pa1b : pa1a;
#pragma unroll
      for (int dn = 0; dn < 8; ++dn)
        oacc[1][dn] = __builtin_amdgcn_mfma_f32_16x16x32_bf16(pa1, vb[dn], oacc[1][dn], 0, 0, 0);
      if (aAct) {
        bf16x8 pa0 = ks2 ? pa0b : pa0a;
#pragma unroll
        for (int dn = 0; dn < 8; ++dn)
          oacc[0][dn] = __builtin_amdgcn_mfma_f32_16x16x32_bf16(pa0, vb[dn], oacc[0][dn], 0, 0, 0);
      }
    }
    __builtin_amdgcn_s_setprio(0);

    __syncthreads();  // drains in-flight stage (had full compute to land) + read fence
  }

#pragma unroll
  for (int t = 0; t < 2; ++t) {
    const int qt = t ? qt1 : qt0;
    unsigned short* ob = Om + (size_t)(qt * 64 + wave * 16) * HID + h * DH;
#pragma unroll
    for (int dn = 0; dn < 8; ++dn)
#pragma unroll
      for (int r = 0; r < 4; ++r)
        ob[(size_t)(lhi * 4 + r) * HID + dn * 16 + llo] = f2bf(oacc[t][dn][r] / lrow[t][r]);
  }
}

extern "C" void kernel_launch(void* const* d_in, const int* in_sizes, int n_in,
                              void* d_out, int out_size, void* d_ws, size_t ws_size,
                              hipStream_t stream) {
  const float* x = (const float*)d_in[0];
  const float* cosT = (const float*)d_in[1];
  const float* sinT = (const float*)d_in[2];
  const float* wq = (const float*)d_in[4];
  const float* wk = (const float*)d_in[5];
  const float* wv = (const float*)d_in[6];
  const float* wo = (const float*)d_in[7];

  float* out = (float*)d_out;
  float* ck_out = out + (size_t)SEQ * HID;
  float* cv_out = ck_out + (size_t)MAXB * NKV * (DH / 8) * MAXS * 8;

  char* ws = (char*)d_ws;
  size_t off = 0;
  auto alloc = [&](size_t bytes) {
    char* p = ws + off;
    off += (bytes + 255) & ~(size_t)255;
    return p;
  };
  unsigned short* x_bf = (unsigned short*)alloc((size_t)SEQ * HID * 2);
  unsigned short* wqkvT = (unsigned short*)alloc((size_t)6144 * HID * 2);
  unsigned short* woT = (unsigned short*)alloc((size_t)HID * HID * 2);
  unsigned short* q_bf = (unsigned short*)alloc((size_t)SEQ * HID * 2);
  unsigned short* k_bf = (unsigned short*)alloc((size_t)SEQ * NKV * DH * 2);
  unsigned short* v_bf = (unsigned short*)alloc((size_t)SEQ * NKV * DH * 2);
  unsigned short* v_t = (unsigned short*)alloc((size_t)NKV * DH * SEQ * 2);
  unsigned short* attn_bf = (unsigned short*)alloc((size_t)SEQ * HID * 2);

  // 1) x -> bf16
  k_cvt_bf16<<<(SEQ * HID / 4) / 256, 256, 0, stream>>>((const float4*)x, (ushort4*)x_bf,
                                                        SEQ * HID / 4);
  // 2) ALL weight transposes in one launch (z: wq, wk, wv, wo)
  k_transpose_all<<<dim3(HID / 64, HID / 64, 4), 256, 0, stream>>>(wq, wk, wv, wo, wqkvT,
                                                                   woT);
  // 3) fused QKV projection + RoPE + cache epilogue: grid 16x16 = 256 (full fill)
  k_gemm<1, 3, true><<<dim3(6144 / 384, SEQ / 128), 512, 0, stream>>>(
      x_bf, wqkvT, nullptr, SEQ, 6144, HID, cosT, sinT, q_bf, k_bf, ck_out, cv_out, v_bf);
  // 4) V^T for attention B-fragments
  k_vt_cvt<<<dim3(SEQ / 32, DH / 32, NKV), dim3(32, 8), 0, stream>>>(v_bf, v_t);
  // 5) cache tails b=1..3: reference caches are zero-initialized -> memset
  {
    const size_t slab = (size_t)NKV * (DH / 8) * MAXS * 8;  // floats (== NKV*MAXS*DH)
    hipMemsetAsync(ck_out + slab, 0, 3 * slab * sizeof(float), stream);
    hipMemsetAsync(cv_out + slab, 0, 3 * slab * sizeof(float), stream);
  }
  // 6) attention (paired q-tiles, double-buffered K/V staging)
  k_attn<<<dim3(16, NH), 256, 0, stream>>>(q_bf, k_bf, v_t, attn_bf);
  // 7) output projection: 128x128 tiles, 64KB LDS -> grid 32x16 = 512 = 2 blocks/CU
  //    (cross-block overlap: one block's MFMA hides the other's LDS-read/barrier stall)
  k_gemm<1, 1, false><<<dim3(HID / 128, SEQ / 128), 512, 0, stream>>>(
      attn_bf, woT, out, SEQ, HID, HID, nullptr, nullptr, nullptr, nullptr, nullptr, nullptr,
      nullptr);
}